// Round 1
// baseline (371.083 us; speedup 1.0000x reference)
//
#include <hip/hip_runtime.h>

#define B_DIM 2048
#define C_DIM 32000
#define MARGIN 1.0f
#define NTHREADS 256

__device__ __forceinline__ float waveReduceSum(float v) {
    #pragma unroll
    for (int off = 32; off > 0; off >>= 1)
        v += __shfl_down(v, off, 64);
    return v;
}

__global__ __launch_bounds__(NTHREADS) void row_loss_kernel(
        const float* __restrict__ scores,
        const int* __restrict__ targets,
        float* __restrict__ row_loss) {
    const int b = blockIdx.x;
    const int tid = threadIdx.x;
    const int lane = tid & 63;
    const int wave = tid >> 6;

    const float* row = scores + (size_t)b * C_DIM;

    __shared__ float s_gt;
    if (tid == 0) s_gt = row[targets[b]];
    __syncthreads();
    const float gt = s_gt;
    const float thr = gt - MARGIN;   // s > thr  <=>  1 + s - gt > 0

    int   cntG = 0;    // # scores strictly greater than gt
    float cntP = 0.f;  // # hinge-positive (incl. target elem, fixed later)
    float sumH = 0.f;  // hinge sum (incl. target elem's exact 1.0, fixed later)

    const float4* row4 = (const float4*)row;
    const int n4 = C_DIM / 4;  // 8000
    for (int i = tid; i < n4; i += NTHREADS) {
        float4 v = row4[i];
        cntG += (v.x > gt); cntG += (v.y > gt); cntG += (v.z > gt); cntG += (v.w > gt);
        if (v.x > thr) { cntP += 1.f; sumH += (MARGIN + v.x - gt); }
        if (v.y > thr) { cntP += 1.f; sumH += (MARGIN + v.y - gt); }
        if (v.z > thr) { cntP += 1.f; sumH += (MARGIN + v.z - gt); }
        if (v.w > thr) { cntP += 1.f; sumH += (MARGIN + v.w - gt); }
    }

    __shared__ float red[4][4];
    float cg = waveReduceSum((float)cntG);
    float cp = waveReduceSum(cntP);
    float sh = waveReduceSum(sumH);
    if (lane == 0) { red[wave][0] = cg; red[wave][1] = cp; red[wave][2] = sh; }
    __syncthreads();

    __shared__ int   s_rank;
    __shared__ float s_np, s_sh;
    if (tid == 0) {
        float tg = 0.f, tp = 0.f, th = 0.f;
        #pragma unroll
        for (int w = 0; w < 4; ++w) { tg += red[w][0]; tp += red[w][1]; th += red[w][2]; }
        s_rank = (int)tg + 1;     // rank of ground truth (1-based)
        s_np   = tp - 1.0f;       // remove the target element (contributed exactly 1)
        s_sh   = th - 1.0f;       // remove target's hinge term (exactly 1.0f)
    }
    __syncthreads();

    // Harmonic number H(rank) = sum_{k=1}^{rank} 1/k, block-parallel.
    const int rank = s_rank;
    float h = 0.f;
    for (int k = tid + 1; k <= rank; k += NTHREADS) h += 1.0f / (float)k;
    h = waveReduceSum(h);
    if (lane == 0) red[wave][3] = h;
    __syncthreads();

    if (tid == 0) {
        float H = red[0][3] + red[1][3] + red[2][3] + red[3][3];
        float loss = H / (s_np + 1e-7f) * s_sh;
        row_loss[b] = loss;
    }
}

__global__ __launch_bounds__(NTHREADS) void mean_kernel(
        const float* __restrict__ row_loss, float* __restrict__ out) {
    const int tid = threadIdx.x;
    float s = 0.f;
    for (int i = tid; i < B_DIM; i += NTHREADS) s += row_loss[i];
    s = waveReduceSum(s);
    __shared__ float red[4];
    const int lane = tid & 63, wave = tid >> 6;
    if (lane == 0) red[wave] = s;
    __syncthreads();
    if (tid == 0) out[0] = (red[0] + red[1] + red[2] + red[3]) * (1.0f / (float)B_DIM);
}

extern "C" void kernel_launch(void* const* d_in, const int* in_sizes, int n_in,
                              void* d_out, int out_size, void* d_ws, size_t ws_size,
                              hipStream_t stream) {
    const float* scores  = (const float*)d_in[0];
    const int*   targets = (const int*)d_in[1];
    float* row_loss = (float*)d_ws;           // 2048 floats of scratch
    float* out      = (float*)d_out;

    row_loss_kernel<<<B_DIM, NTHREADS, 0, stream>>>(scores, targets, row_loss);
    mean_kernel<<<1, NTHREADS, 0, stream>>>(row_loss, out);
}

// Round 2
// 357.381 us; speedup vs baseline: 1.0383x; 1.0383x over previous
//
#include <hip/hip_runtime.h>
#include <math.h>

#define B_DIM 2048
#define C_DIM 32000
#define MARGIN 1.0f
#define NTHREADS 256

__device__ __forceinline__ float waveReduceSum(float v) {
    #pragma unroll
    for (int off = 32; off > 0; off >>= 1)
        v += __shfl_down(v, off, 64);
    return v;
}

__device__ __forceinline__ void acc4(float4 v, float gt, float thr,
                                     int& cntG, int& cntP, float& sumH) {
    // branch-free: d = MARGIN + s - gt computed as s - (gt - MARGIN)
    cntG += (v.x > gt); cntG += (v.y > gt); cntG += (v.z > gt); cntG += (v.w > gt);
    float dx = v.x - thr, dy = v.y - thr, dz = v.z - thr, dw = v.w - thr;
    cntP += (dx > 0.f); cntP += (dy > 0.f); cntP += (dz > 0.f); cntP += (dw > 0.f);
    sumH += fmaxf(dx, 0.f); sumH += fmaxf(dy, 0.f);
    sumH += fmaxf(dz, 0.f); sumH += fmaxf(dw, 0.f);
}

__global__ __launch_bounds__(NTHREADS) void row_loss_kernel(
        const float* __restrict__ scores,
        const int* __restrict__ targets,
        float* __restrict__ row_loss) {
    const int b = blockIdx.x;
    const int tid = threadIdx.x;
    const int lane = tid & 63;
    const int wave = tid >> 6;

    const float* __restrict__ row = scores + (size_t)b * C_DIM;

    // b is uniform -> these lower to scalar loads; no barrier needed.
    const int tgt  = targets[b];
    const float gt = row[tgt];
    const float thr = gt - MARGIN;

    int   cntG = 0;    // # scores strictly greater than gt
    int   cntP = 0;    // # hinge-positive (incl. target elem, fixed later)
    float sumH = 0.f;  // hinge sum (incl. target's exact 1.0, fixed later)

    const float4* __restrict__ row4 = (const float4*)row;
    const float4* p = row4 + tid;
    // 8000 float4 per row = 7*(4*256) + 3*256 + 64
    #pragma unroll 1
    for (int k = 0; k < 7; ++k) {
        float4 a0 = p[0];
        float4 a1 = p[NTHREADS];
        float4 a2 = p[2 * NTHREADS];
        float4 a3 = p[3 * NTHREADS];
        acc4(a0, gt, thr, cntG, cntP, sumH);
        acc4(a1, gt, thr, cntG, cntP, sumH);
        acc4(a2, gt, thr, cntG, cntP, sumH);
        acc4(a3, gt, thr, cntG, cntP, sumH);
        p += 4 * NTHREADS;
    }
    {
        float4 a0 = p[0];
        float4 a1 = p[NTHREADS];
        float4 a2 = p[2 * NTHREADS];
        acc4(a0, gt, thr, cntG, cntP, sumH);
        acc4(a1, gt, thr, cntG, cntP, sumH);
        acc4(a2, gt, thr, cntG, cntP, sumH);
    }
    if (tid < 64) {
        float4 a0 = row4[7936 + tid];
        acc4(a0, gt, thr, cntG, cntP, sumH);
    }

    float cg = waveReduceSum((float)cntG);
    float cp = waveReduceSum((float)cntP);
    float sh = waveReduceSum(sumH);

    __shared__ float red[4][3];
    if (lane == 0) { red[wave][0] = cg; red[wave][1] = cp; red[wave][2] = sh; }
    __syncthreads();

    if (tid == 0) {
        float tg = 0.f, tp = 0.f, th = 0.f;
        #pragma unroll
        for (int w = 0; w < 4; ++w) { tg += red[w][0]; tp += red[w][1]; th += red[w][2]; }
        int rank = (int)tg + 1;       // 1-based rank of ground truth
        float n_pos = tp - 1.0f;      // remove target element (contributed exactly 1)
        float hinge = th - 1.0f;      // remove target's hinge term (exactly 1.0f)

        // H(rank): asymptotic expansion (err < 1e-8 for rank>=40), direct sum else.
        float H;
        if (rank >= 40) {
            float n = (float)rank;
            float inv = 1.0f / n;
            H = logf(n) + 0.57721566f + 0.5f * inv - (1.0f / 12.0f) * inv * inv;
        } else {
            H = 0.f;
            for (int k = 1; k <= rank; ++k) H += 1.0f / (float)k;
        }
        row_loss[b] = H / (n_pos + 1e-7f) * hinge;
    }
}

__global__ __launch_bounds__(NTHREADS) void mean_kernel(
        const float* __restrict__ row_loss, float* __restrict__ out) {
    const int tid = threadIdx.x;
    float s = 0.f;
    for (int i = tid; i < B_DIM; i += NTHREADS) s += row_loss[i];
    s = waveReduceSum(s);
    __shared__ float red[4];
    const int lane = tid & 63, wave = tid >> 6;
    if (lane == 0) red[wave] = s;
    __syncthreads();
    if (tid == 0) out[0] = (red[0] + red[1] + red[2] + red[3]) * (1.0f / (float)B_DIM);
}

extern "C" void kernel_launch(void* const* d_in, const int* in_sizes, int n_in,
                              void* d_out, int out_size, void* d_ws, size_t ws_size,
                              hipStream_t stream) {
    const float* scores  = (const float*)d_in[0];
    const int*   targets = (const int*)d_in[1];
    float* row_loss = (float*)d_ws;   // 2048 floats of scratch
    float* out      = (float*)d_out;

    row_loss_kernel<<<B_DIM, NTHREADS, 0, stream>>>(scores, targets, row_loss);
    mean_kernel<<<1, NTHREADS, 0, stream>>>(row_loss, out);
}

// Round 4
// 335.096 us; speedup vs baseline: 1.1074x; 1.0665x over previous
//
#include <hip/hip_runtime.h>
#include <math.h>

#define B_DIM 2048
#define C_DIM 32000
#define MARGIN 1.0f
#define NTHREADS 256

typedef float vfloat4 __attribute__((ext_vector_type(4)));

__device__ __forceinline__ float waveReduceSum(float v) {
    #pragma unroll
    for (int off = 32; off > 0; off >>= 1)
        v += __shfl_down(v, off, 64);
    return v;
}

__device__ __forceinline__ void acc4(vfloat4 v, float gt, float thr,
                                     int& cntG, int& cntP, float& sumH) {
    cntG += (v.x > gt); cntG += (v.y > gt); cntG += (v.z > gt); cntG += (v.w > gt);
    float dx = v.x - thr, dy = v.y - thr, dz = v.z - thr, dw = v.w - thr;
    cntP += (dx > 0.f); cntP += (dy > 0.f); cntP += (dz > 0.f); cntP += (dw > 0.f);
    sumH += fmaxf(dx, 0.f); sumH += fmaxf(dy, 0.f);
    sumH += fmaxf(dz, 0.f); sumH += fmaxf(dw, 0.f);
}

__device__ __forceinline__ vfloat4 ntload(const vfloat4* p) {
    return __builtin_nontemporal_load(p);
}

__global__ void zero_out_kernel(float* __restrict__ out) {
    if (threadIdx.x == 0) out[0] = 0.f;
}

__global__ __launch_bounds__(NTHREADS) void row_loss_kernel(
        const float* __restrict__ scores,
        const int* __restrict__ targets,
        float* __restrict__ out) {
    const int b = blockIdx.x;
    const int tid = threadIdx.x;
    const int lane = tid & 63;
    const int wave = tid >> 6;

    const float* __restrict__ row = scores + (size_t)b * C_DIM;

    // b is uniform -> scalar loads; no barrier needed.
    const int tgt  = targets[b];
    const float gt = row[tgt];
    const float thr = gt - MARGIN;

    int   cntG = 0;    // # scores strictly greater than gt
    int   cntP = 0;    // # hinge-positive (incl. target elem, fixed later)
    float sumH = 0.f;  // hinge sum (incl. target's exact 1.0, fixed later)

    const vfloat4* __restrict__ row4 = (const vfloat4*)row;
    const vfloat4* p = row4 + tid;
    // 8000 float4 per row = 3*(8*256) + 7*256 + 64
    #pragma unroll 1
    for (int k = 0; k < 3; ++k) {
        vfloat4 a0 = ntload(p);
        vfloat4 a1 = ntload(p + NTHREADS);
        vfloat4 a2 = ntload(p + 2 * NTHREADS);
        vfloat4 a3 = ntload(p + 3 * NTHREADS);
        vfloat4 a4 = ntload(p + 4 * NTHREADS);
        vfloat4 a5 = ntload(p + 5 * NTHREADS);
        vfloat4 a6 = ntload(p + 6 * NTHREADS);
        vfloat4 a7 = ntload(p + 7 * NTHREADS);
        acc4(a0, gt, thr, cntG, cntP, sumH);
        acc4(a1, gt, thr, cntG, cntP, sumH);
        acc4(a2, gt, thr, cntG, cntP, sumH);
        acc4(a3, gt, thr, cntG, cntP, sumH);
        acc4(a4, gt, thr, cntG, cntP, sumH);
        acc4(a5, gt, thr, cntG, cntP, sumH);
        acc4(a6, gt, thr, cntG, cntP, sumH);
        acc4(a7, gt, thr, cntG, cntP, sumH);
        p += 8 * NTHREADS;
    }
    {   // 7*256 float4
        vfloat4 a0 = ntload(p);
        vfloat4 a1 = ntload(p + NTHREADS);
        vfloat4 a2 = ntload(p + 2 * NTHREADS);
        vfloat4 a3 = ntload(p + 3 * NTHREADS);
        vfloat4 a4 = ntload(p + 4 * NTHREADS);
        vfloat4 a5 = ntload(p + 5 * NTHREADS);
        vfloat4 a6 = ntload(p + 6 * NTHREADS);
        acc4(a0, gt, thr, cntG, cntP, sumH);
        acc4(a1, gt, thr, cntG, cntP, sumH);
        acc4(a2, gt, thr, cntG, cntP, sumH);
        acc4(a3, gt, thr, cntG, cntP, sumH);
        acc4(a4, gt, thr, cntG, cntP, sumH);
        acc4(a5, gt, thr, cntG, cntP, sumH);
        acc4(a6, gt, thr, cntG, cntP, sumH);
    }
    if (tid < 64) {
        vfloat4 a0 = ntload(row4 + 7936 + tid);
        acc4(a0, gt, thr, cntG, cntP, sumH);
    }

    float cg = waveReduceSum((float)cntG);
    float cp = waveReduceSum((float)cntP);
    float sh = waveReduceSum(sumH);

    __shared__ float red[4][3];
    if (lane == 0) { red[wave][0] = cg; red[wave][1] = cp; red[wave][2] = sh; }
    __syncthreads();

    if (tid == 0) {
        float tg = 0.f, tp = 0.f, th = 0.f;
        #pragma unroll
        for (int w = 0; w < 4; ++w) { tg += red[w][0]; tp += red[w][1]; th += red[w][2]; }
        int rank = (int)tg + 1;       // 1-based rank of ground truth
        float n_pos = tp - 1.0f;      // remove target element (contributed exactly 1)
        float hinge = th - 1.0f;      // remove target's hinge term (exactly 1.0f)

        // H(rank): asymptotic expansion (err < 1e-8 for rank>=40), direct sum else.
        float H;
        if (rank >= 40) {
            float n = (float)rank;
            float inv = 1.0f / n;
            H = logf(n) + 0.57721566f + 0.5f * inv - (1.0f / 12.0f) * inv * inv;
        } else {
            H = 0.f;
            for (int k = 1; k <= rank; ++k) H += 1.0f / (float)k;
        }
        float loss = H / (n_pos + 1e-7f) * hinge;
        atomicAdd(out, loss * (1.0f / (float)B_DIM));
    }
}

extern "C" void kernel_launch(void* const* d_in, const int* in_sizes, int n_in,
                              void* d_out, int out_size, void* d_ws, size_t ws_size,
                              hipStream_t stream) {
    const float* scores  = (const float*)d_in[0];
    const int*   targets = (const int*)d_in[1];
    float* out = (float*)d_out;

    zero_out_kernel<<<1, 64, 0, stream>>>(out);
    row_loss_kernel<<<B_DIM, NTHREADS, 0, stream>>>(scores, targets, out);
}

// Round 5
// 333.150 us; speedup vs baseline: 1.1139x; 1.0058x over previous
//
#include <hip/hip_runtime.h>
#include <math.h>

#define B_DIM 2048
#define C_DIM 32000
#define MARGIN 1.0f
#define NTHREADS 256

typedef float vfloat4 __attribute__((ext_vector_type(4)));

__device__ __forceinline__ float waveReduceSum(float v) {
    #pragma unroll
    for (int off = 32; off > 0; off >>= 1)
        v += __shfl_down(v, off, 64);
    return v;
}

// 6 VALU / element: cmp+addc (rank), cmp+addc (n_pos), max+add (hinge partial)
__device__ __forceinline__ void acc4(vfloat4 v, float gt, float thr,
                                     int& cntG, int& cntP, float& sumM) {
    cntG += (v.x > gt); cntG += (v.y > gt); cntG += (v.z > gt); cntG += (v.w > gt);
    cntP += (v.x > thr); cntP += (v.y > thr); cntP += (v.z > thr); cntP += (v.w > thr);
    sumM += fmaxf(v.x, thr); sumM += fmaxf(v.y, thr);
    sumM += fmaxf(v.z, thr); sumM += fmaxf(v.w, thr);
}

__device__ __forceinline__ vfloat4 ntload(const vfloat4* p) {
    return __builtin_nontemporal_load(p);
}

__global__ __launch_bounds__(NTHREADS) void row_loss_kernel(
        const float* __restrict__ scores,
        const int* __restrict__ targets,
        float* __restrict__ out) {
    const int b = blockIdx.x;
    const int tid = threadIdx.x;
    const int lane = tid & 63;
    const int wave = tid >> 6;

    const float* __restrict__ row = scores + (size_t)b * C_DIM;

    // b is uniform -> scalar loads; no barrier needed.
    const int tgt  = targets[b];
    const float gt = row[tgt];
    const float thr = gt - MARGIN;

    int   cntG = 0;    // # scores strictly greater than gt
    int   cntP = 0;    // # scores > thr (incl. target, fixed later)
    float sumM = 0.f;  // sum of max(s, thr); hinge = sumM - C*thr

    const vfloat4* __restrict__ row4 = (const vfloat4*)row;
    // 8000 float4 = 31 full groups of 256 + one 64-wide tail group.
    // Software pipeline, 8 loads always in flight until the tail.
    vfloat4 buf[8];
    #pragma unroll
    for (int j = 0; j < 8; ++j)
        buf[j] = ntload(row4 + tid + j * NTHREADS);

    #pragma unroll
    for (int j = 0; j < 31; ++j) {
        vfloat4 v = buf[j & 7];
        if (j + 8 < 31) {
            buf[j & 7] = ntload(row4 + tid + (j + 8) * NTHREADS);
        } else if (j + 8 == 31) {
            if (tid < 64) buf[j & 7] = ntload(row4 + 7936 + tid);
        }
        acc4(v, gt, thr, cntG, cntP, sumM);
    }
    if (tid < 64) {
        // tail group sits in slot (23 & 7) == 7
        acc4(buf[7], gt, thr, cntG, cntP, sumM);
    }
    // lanes with tid>=64 contributed no tail; their sumM has 31*4 terms,
    // tid<64 lanes have 32*4 — bookkeeping below uses totals, all exact.

    float cg = waveReduceSum((float)cntG);
    float cp = waveReduceSum((float)cntP);
    float sm = waveReduceSum(sumM);

    __shared__ float red[4][3];
    if (lane == 0) { red[wave][0] = cg; red[wave][1] = cp; red[wave][2] = sm; }
    __syncthreads();

    if (tid == 0) {
        float tg = 0.f, tp = 0.f, tm = 0.f;
        #pragma unroll
        for (int w = 0; w < 4; ++w) { tg += red[w][0]; tp += red[w][1]; tm += red[w][2]; }
        int rank = (int)tg + 1;              // 1-based rank of ground truth
        float n_pos = tp - 1.0f;             // remove target element
        // hinge over all elements incl. target = sum(max(s,thr)) - C*thr;
        // target contributes exactly (gt - thr) = 1.0f -> subtract it.
        float hinge = (tm - (float)C_DIM * thr) - 1.0f;

        // H(rank): asymptotic expansion (err < 1e-8 for rank>=40), direct sum else.
        float H;
        if (rank >= 40) {
            float n = (float)rank;
            float inv = 1.0f / n;
            H = logf(n) + 0.57721566f + 0.5f * inv - (1.0f / 12.0f) * inv * inv;
        } else {
            H = 0.f;
            for (int k = 1; k <= rank; ++k) H += 1.0f / (float)k;
        }
        float loss = H / (n_pos + 1e-7f) * hinge;
        atomicAdd(out, loss * (1.0f / (float)B_DIM));
    }
}

extern "C" void kernel_launch(void* const* d_in, const int* in_sizes, int n_in,
                              void* d_out, int out_size, void* d_ws, size_t ws_size,
                              hipStream_t stream) {
    const float* scores  = (const float*)d_in[0];
    const int*   targets = (const int*)d_in[1];
    float* out = (float*)d_out;

    hipMemsetAsync(out, 0, sizeof(float), stream);
    row_loss_kernel<<<B_DIM, NTHREADS, 0, stream>>>(scores, targets, out);
}